// Round 14
// baseline (473.713 us; speedup 1.0000x reference)
//
#include <hip/hip_runtime.h>
#include <math.h>

// SimpleRetention bf16 MFMA, round 17:
//  - NEW: qk_8phase — derived-waits 8-phase 256^2 kernel for the Q,K
//    projection (the 146us/46% dominant dispatch). Stage units matched to
//    read-deadlines; counted vmcnt(2)/(4)/(4) per tile, never 0 mid-loop.
//  - All other stages frozen at the round-14 config (best 411.0us):
//    fused att(360)+V-proj(1024); s4 BN=128 XCD-chunked; banded att; cvt.

typedef __attribute__((ext_vector_type(8))) short short8;
typedef __attribute__((ext_vector_type(4))) float f32x4;
typedef __attribute__((ext_vector_type(4))) unsigned short us4;

#define BM 128
#define ABAND 384

static __device__ __forceinline__ unsigned short f2bf(float f) {
    unsigned int u = __float_as_uint(f);
    u += 0x7FFFu + ((u >> 16) & 1u);   // RNE
    return (unsigned short)(u >> 16);
}

static __device__ __forceinline__ void gload16(const unsigned short* g, unsigned short* l) {
    __builtin_amdgcn_global_load_lds(
        (const __attribute__((address_space(1))) unsigned int*)g,
        (__attribute__((address_space(3))) unsigned int*)l, 16, 0, 0);
}

#define MFMA __builtin_amdgcn_mfma_f32_16x16x32_bf16

// ---------------- 8-phase Q,K projection (256x256 tile, 8 waves) ----------
// LDS [2buf][256 rows][64 k] for A and B; chunk-XOR swizzle (row r, chunk p
// holds source chunk p^(r&7)). Stage units (16KB = 2 gload16/thread):
//   U1 = A rows {0-63,128-191}   (read at P1)
//   U2 = B rows, (R>>5) even     (read at P1, re-read P3)
//   U3 = B rows, (R>>5) odd      (read at P2, re-read P4)
//   U4 = A rows {64-127,192-255} (read at P3)
// Staging of tile t+1 into buf^1: U1,U2 @P2, U3 @P3, U4 @P4.
// vmcnt: P1 (2) retires U3(t); P2 (4) retires U4(t); P4 (4) retires U1,U2(t+1).
__global__ __launch_bounds__(512, 2)
void qk_8phase(const unsigned short* __restrict__ A,   // Xb  [8192][2048]
               const unsigned short* __restrict__ Bt,  // WtAll rows 0..4095 = WtQ;WtK
               unsigned short* __restrict__ Cq,
               unsigned short* __restrict__ Ck)
{
    constexpr int S = 2048, H = 2048, NT = 2048 / 64;
    const int rowBase = blockIdx.y * 256;
    const int colBase = blockIdx.x * 256;

    __shared__ unsigned short As[32768]; // [2][256][64]
    __shared__ unsigned short Bs[32768];

    const int tid  = threadIdx.x;
    const int wave = tid >> 6;
    const int lane = tid & 63;
    const int wm = (wave >> 2) * 128;
    const int wn = (wave & 3) * 64;

    const int row8 = lane >> 3;
    const int csw  = ((lane & 7) ^ row8) * 8;

    f32x4 acc[8][4];
#pragma unroll
    for (int i = 0; i < 8; ++i)
#pragma unroll
        for (int j = 0; j < 4; ++j) acc[i][j] = (f32x4){0.f, 0.f, 0.f, 0.f};

    auto stgA = [&](int t1, int b1, int u) {
#pragma unroll
        for (int g = 0; g < 2; ++g) {
            int s0 = g * 64 + wave * 8;
            int R0 = (s0 < 64 ? s0 : s0 + 64) + u * 64;
            gload16(A + (size_t)(rowBase + R0 + row8) * H + t1 * 64 + csw,
                    As + b1 * 16384 + R0 * 64);
        }
    };
    auto stgB = [&](int t1, int b1, int q) {
#pragma unroll
        for (int g = 0; g < 2; ++g) {
            int s0 = g * 64 + wave * 8;
            int R0 = ((s0 >> 5) << 6) + q * 32 + (s0 & 31);
            gload16(Bt + (size_t)(colBase + R0 + row8) * H + t1 * 64 + csw,
                    Bs + b1 * 16384 + R0 * 64);
        }
    };

    // prologue: tile 0, issue order U1,U2,U3,U4; retire U1,U2.
    stgA(0, 0, 0); stgB(0, 0, 0); stgB(0, 0, 1); stgA(0, 0, 1);
    __builtin_amdgcn_sched_barrier(0);
    asm volatile("s_waitcnt vmcnt(4)" ::: "memory");
    __builtin_amdgcn_sched_barrier(0);
    __builtin_amdgcn_s_barrier();
    asm volatile("" ::: "memory");

    const int fr  = lane & 15;
    const int qd  = lane >> 4;
    const int fsw = fr & 7;
    const int c0  = (qd ^ fsw) * 8;
    const int c1  = ((4 + qd) ^ fsw) * 8;
    const int aRow = wm + fr;
    const int bRow = wn + fr;

    for (int t = 0; t < NT; ++t) {
        const int b = t & 1;
        const unsigned short* Ab = As + b * 16384;
        const unsigned short* Bb = Bs + b * 16384;
        const bool pf = (t + 1 < NT);
        short8 aF[4][2], bF[2][2], bG[2][2];

        // ---- P1: i0-3 x j0-1 (12 ds_reads) ----
#pragma unroll
        for (int i = 0; i < 4; ++i) {
            aF[i][0] = *(const short8*)&Ab[(aRow + i * 16) * 64 + c0];
            aF[i][1] = *(const short8*)&Ab[(aRow + i * 16) * 64 + c1];
        }
#pragma unroll
        for (int j = 0; j < 2; ++j) {
            bF[j][0] = *(const short8*)&Bb[(bRow + j * 16) * 64 + c0];
            bF[j][1] = *(const short8*)&Bb[(bRow + j * 16) * 64 + c1];
        }
        __builtin_amdgcn_sched_barrier(0);
        asm volatile("s_waitcnt vmcnt(2)" ::: "memory");
        __builtin_amdgcn_sched_barrier(0);
        __builtin_amdgcn_s_barrier();
        __builtin_amdgcn_s_setprio(1);
#pragma unroll
        for (int i = 0; i < 4; ++i)
#pragma unroll
            for (int j = 0; j < 2; ++j) {
                acc[i][j] = MFMA(aF[i][0], bF[j][0], acc[i][j], 0, 0, 0);
                acc[i][j] = MFMA(aF[i][1], bF[j][1], acc[i][j], 0, 0, 0);
            }
        __builtin_amdgcn_s_setprio(0);
        __builtin_amdgcn_s_barrier();

        // ---- P2: i0-3 x j2-3 (4 ds_reads; stage U1,U2(t+1)) ----
#pragma unroll
        for (int j = 0; j < 2; ++j) {
            bG[j][0] = *(const short8*)&Bb[(bRow + 32 + j * 16) * 64 + c0];
            bG[j][1] = *(const short8*)&Bb[(bRow + 32 + j * 16) * 64 + c1];
        }
        if (pf) { stgA(t + 1, b ^ 1, 0); stgB(t + 1, b ^ 1, 0); }
        __builtin_amdgcn_sched_barrier(0);
        if (pf) { asm volatile("s_waitcnt vmcnt(4)" ::: "memory"); }
        else    { asm volatile("s_waitcnt vmcnt(0)" ::: "memory"); }
        __builtin_amdgcn_sched_barrier(0);
        __builtin_amdgcn_s_barrier();
        __builtin_amdgcn_s_setprio(1);
#pragma unroll
        for (int i = 0; i < 4; ++i)
#pragma unroll
            for (int j = 0; j < 2; ++j) {
                acc[i][j + 2] = MFMA(aF[i][0], bG[j][0], acc[i][j + 2], 0, 0, 0);
                acc[i][j + 2] = MFMA(aF[i][1], bG[j][1], acc[i][j + 2], 0, 0, 0);
            }
        __builtin_amdgcn_s_setprio(0);
        __builtin_amdgcn_s_barrier();

        // ---- P3: i4-7 x j0-1 (12 ds_reads; stage U3(t+1)) ----
#pragma unroll
        for (int i = 0; i < 4; ++i) {
            aF[i][0] = *(const short8*)&Ab[(aRow + 64 + i * 16) * 64 + c0];
            aF[i][1] = *(const short8*)&Ab[(aRow + 64 + i * 16) * 64 + c1];
        }
#pragma unroll
        for (int j = 0; j < 2; ++j) {
            bF[j][0] = *(const short8*)&Bb[(bRow + j * 16) * 64 + c0];
            bF[j][1] = *(const short8*)&Bb[(bRow + j * 16) * 64 + c1];
        }
        if (pf) stgB(t + 1, b ^ 1, 1);
        __builtin_amdgcn_sched_barrier(0);
        __builtin_amdgcn_s_barrier();
        __builtin_amdgcn_s_setprio(1);
#pragma unroll
        for (int i = 0; i < 4; ++i)
#pragma unroll
            for (int j = 0; j < 2; ++j) {
                acc[i + 4][j] = MFMA(aF[i][0], bF[j][0], acc[i + 4][j], 0, 0, 0);
                acc[i + 4][j] = MFMA(aF[i][1], bF[j][1], acc[i + 4][j], 0, 0, 0);
            }
        __builtin_amdgcn_s_setprio(0);
        __builtin_amdgcn_s_barrier();

        // ---- P4: i4-7 x j2-3 (4 ds_reads; stage U4(t+1)) ----
#pragma unroll
        for (int j = 0; j < 2; ++j) {
            bG[j][0] = *(const short8*)&Bb[(bRow + 32 + j * 16) * 64 + c0];
            bG[j][1] = *(const short8*)&Bb[(bRow + 32 + j * 16) * 64 + c1];
        }
        if (pf) stgA(t + 1, b ^ 1, 1);
        __builtin_amdgcn_sched_barrier(0);
        if (pf) { asm volatile("s_waitcnt vmcnt(4)" ::: "memory"); }
        else    { asm volatile("s_waitcnt vmcnt(0)" ::: "memory"); }
        __builtin_amdgcn_sched_barrier(0);
        __builtin_amdgcn_s_barrier();
        __builtin_amdgcn_s_setprio(1);
#pragma unroll
        for (int i = 0; i < 4; ++i)
#pragma unroll
            for (int j = 0; j < 2; ++j) {
                acc[i + 4][j + 2] = MFMA(aF[i][0], bG[j][0], acc[i + 4][j + 2], 0, 0, 0);
                acc[i + 4][j + 2] = MFMA(aF[i][1], bG[j][1], acc[i + 4][j + 2], 0, 0, 0);
            }
        __builtin_amdgcn_s_setprio(0);
        __builtin_amdgcn_s_barrier();
        asm volatile("" ::: "memory");
    }

    // epilogue: xpos (verified 256^2 mapping from round-2 kernel, bit-identical)
    const int mode = colBase >> 11; // 0=Q, 1=K
    unsigned short* Co = (mode == 0) ? Cq : Ck;
    const float psgn = (mode == 1) ? -1.953125e-3f : 1.953125e-3f; // ±1/512
#pragma unroll
    for (int j = 0; j < 4; ++j) {
        int gc = (colBase & 2047) + wn + j * 16 + fr;
        float c0f = (float)(gc & ~1);
        float l2sv = log2f((c0f + 819.2f) * (1.0f / 2867.2f)) * psgn;
        float invf = exp2f(c0f * -0.0064881407f); // 10000^(-c0/2048)
        float s1, c1f;
        sincosf(invf, &s1, &c1f);
#pragma unroll
        for (int i = 0; i < 8; ++i) {
            int gr0 = rowBase + wm + i * 16 + qd * 4;
            float fn = (float)(gr0 & (S - 1));
            float sN, cN;
            sincosf(fn * invf, &sN, &cN);
#pragma unroll
            for (int r = 0; r < 4; ++r) {
                float scale = exp2f(fn * l2sv);
                float cs = cN * scale, ss = sN * scale;
                float v = acc[i][j][r];
                float o = __shfl_xor(v, 1);
                float res = (gc & 1) ? fmaf(v, cs, o * ss) : fmaf(v, cs, -o * ss);
                Co[(size_t)(gr0 + r) * H + gc] = f2bf(res);
                float sn2 = sN * c1f + cN * s1; // rotate by invf
                cN = cN * c1f - sN * s1;
                sN = sn2;
                fn += 1.0f;
            }
        }
    }
}

// ---------------- proven 128-row 2-phase core (att, V-proj, s4) -----------
template <int STAGE, int BNt, int BKt>
static __device__ __forceinline__ void gemm_core(
    const unsigned short* __restrict__ A,
    const unsigned short* __restrict__ Bt,
    void* __restrict__ Cv,
    unsigned short* __restrict__ Cvt,
    int lda, int ldb, int Kd,
    long long sA, long long sB, long long sC,
    int bx, int by, int zb,
    unsigned short* As, unsigned short* Bs)
{
    constexpr int S = 2048, H = 2048;
    constexpr int NJ = BNt / 32;
    constexpr int KS = BKt / 32;
    constexpr int CR = BKt / 8;
    constexpr int RG = 64 / CR;
    constexpr int GA = 32 / RG;
    constexpr int GB = (BNt / 4) / RG;

    const int rowBase = by * BM;
    const int colBase = bx * BNt;

    A  += (long long)zb * sA;
    Bt += (long long)zb * sB;

    const int tid  = threadIdx.x;
    const int wave = tid >> 6;
    const int lane = tid & 63;
    const int wm = (wave & 1) * 64;
    const int wn = (wave >> 1) * (BNt / 2);

    f32x4 acc[4][NJ];
#pragma unroll
    for (int i = 0; i < 4; ++i)
#pragma unroll
        for (int j = 0; j < NJ; ++j) acc[i][j] = (f32x4){0.f, 0.f, 0.f, 0.f};

    int kmax = Kd;
    if (STAGE == 4) { int km = rowBase + BM; kmax = km < Kd ? km : Kd; }
    int k0s = 0;
    if (STAGE == 4) {
        int kb0 = 2 * by - 4; k0s = (kb0 > 0 ? kb0 : 0) * 64;
        A -= k0s;   // banded storage
    }

    const int cpos = lane % CR;
    const int rig  = lane / CR;
    const int waveArow = wave * 32;
    const int waveBrow = wave * (BNt / 4);
    unsigned short* lA = As + wave * (32 * BKt);
    unsigned short* lB = Bs + wave * ((BNt / 4) * BKt);

    auto stage_tile = [&](int kb) {
#pragma unroll
        for (int g = 0; g < GA; ++g) {
            int r = waveArow + g * RG + rig;
            gload16(A + (size_t)(rowBase + r) * lda + kb + ((cpos ^ (r & 7)) * 8),
                    lA + g * 512);
        }
#pragma unroll
        for (int g = 0; g < GB; ++g) {
            int r = waveBrow + g * RG + rig;
            gload16(Bt + (size_t)(colBase + r) * ldb + kb + ((cpos ^ (r & 7)) * 8),
                    lB + g * 512);
        }
    };

    stage_tile(k0s);

    const int fr = lane & 15;
    const int qd = lane >> 4;
    const int fsw = fr & 7;

    for (int k0 = k0s; k0 < kmax; k0 += BKt) {
        __syncthreads();
        short8 aF[KS][4], bF[KS][NJ];
#pragma unroll
        for (int kk = 0; kk < KS; ++kk) {
#pragma unroll
            for (int i = 0; i < 4; ++i)
                aF[kk][i] = *(const short8*)&As[(wm + i * 16 + fr) * BKt + (((kk * 4 + qd) ^ fsw) * 8)];
#pragma unroll
            for (int j = 0; j < NJ; ++j)
                bF[kk][j] = *(const short8*)&Bs[(wn + j * 16 + fr) * BKt + (((kk * 4 + qd) ^ fsw) * 8)];
        }
        __syncthreads();
        if (k0 + BKt < kmax) stage_tile(k0 + BKt);
#pragma unroll
        for (int kk = 0; kk < KS; ++kk)
#pragma unroll
            for (int i = 0; i < 4; ++i)
#pragma unroll
                for (int j = 0; j < NJ; ++j)
                    acc[i][j] = MFMA(aF[kk][i], bF[kk][j], acc[i][j], 0, 0, 0);
    }

    if (STAGE == 1) { // V projection: store transposed Vt[h][8192]
#pragma unroll
        for (int j = 0; j < NJ; ++j) {
            int gh = (colBase & 2047) + wn + j * 16 + fr;
#pragma unroll
            for (int i = 0; i < 4; ++i) {
                int gm0 = rowBase + wm + i * 16 + qd * 4;
                us4 p;
#pragma unroll
                for (int r = 0; r < 4; ++r) p[r] = f2bf(acc[i][j][r]);
                *(us4*)&Cvt[(size_t)gh * 8192 + gm0] = p;
            }
        }
    } else if (STAGE == 3) {
        unsigned short* att = (unsigned short*)Cv + (long long)zb * sC;
        const int kb0 = (2 * by - 4) > 0 ? (2 * by - 4) : 0;
        const int mshift = kb0 * 64;
#pragma unroll
        for (int j = 0; j < NJ; ++j) {
            int m = colBase + wn + j * 16 + fr;
#pragma unroll
            for (int i = 0; i < 4; ++i) {
                int n0 = rowBase + wm + i * 16 + qd * 4;
#pragma unroll
                for (int r = 0; r < 4; ++r) {
                    int d = n0 + r - m;
                    float v = (d >= 0) ? acc[i][j][r] * exp2f((float)d * -0.045803598f) : 0.0f;
                    att[(size_t)(n0 + r) * ABAND + (m - mshift)] = f2bf(v);
                }
            }
        }
    } else { // STAGE 4
        float* Co = (float*)Cv + (long long)zb * sC;
#pragma unroll
        for (int j = 0; j < NJ; ++j) {
            int gh = colBase + wn + j * 16 + fr;
#pragma unroll
            for (int i = 0; i < 4; ++i) {
                int gn0 = rowBase + wm + i * 16 + qd * 4;
#pragma unroll
                for (int r = 0; r < 4; ++r)
                    Co[(size_t)(gn0 + r) * H + gh] = acc[i][j][r];
            }
        }
    }
}

template <int STAGE, int BNt, int BKt>
__global__ __launch_bounds__(256)
void gemm_bt(const unsigned short* __restrict__ A,
             const unsigned short* __restrict__ Bt,
             void* __restrict__ Cv,
             unsigned short* __restrict__ Cvt,
             int lda, int ldb, int Kd,
             long long sA, long long sB, long long sC)
{
    __shared__ unsigned short As[BM * BKt];
    __shared__ unsigned short Bs[BNt * BKt];
    int bx, by, zb;
    if (STAGE == 4) {
        int id = blockIdx.x;
        int swz = (id & 7) * 128 + (id >> 3);
        bx = swz >> 6;
        int r = swz & 63;
        zb = r >> 4;
        by = 15 - (r & 15);
    } else {
        bx = blockIdx.x; by = blockIdx.y; zb = 0;
    }
    gemm_core<STAGE, BNt, BKt>(A, Bt, Cv, Cvt, lda, ldb, Kd,
                               sA, sB, sC, bx, by, zb, As, Bs);
}

// Fused: ids [0,360) = att blocks; ids [360,1384) = V-projection blocks.
__global__ __launch_bounds__(256)
void fused_vatt(const unsigned short* __restrict__ Xb,
                const unsigned short* __restrict__ Wt,
                const unsigned short* __restrict__ Qb,
                const unsigned short* __restrict__ Kb,
                unsigned short* __restrict__ att,
                unsigned short* __restrict__ Vt)
{
    constexpr int S = 2048, H = 2048;
    constexpr long long SH = (long long)S * H;
    constexpr long long SB = (long long)S * ABAND;
    __shared__ unsigned short smem[16384];
    if (blockIdx.x < 360) {
        int t = blockIdx.x;
        int swz = (t & 7) * 45 + (t >> 3);
        int zb = swz / 90;
        int tt = swz - zb * 90;
        int bx, by;
        if (tt < 6) {
            by = (tt < 2) ? 0 : 1;
            bx = tt - ((by == 0) ? 0 : 2);
        } else {
            by = 2 + (tt - 6) / 6;
            int kb0 = 2 * by - 4;
            bx = (kb0 > 0 ? kb0 : 0) + (tt - 6) % 6;
        }
        gemm_core<3, 64, 64>(Qb, Kb, att, nullptr,
                             H, H, H, SH, SH, SB, bx, by, zb,
                             smem, smem + 8192);
    } else {
        int id = blockIdx.x - 360;
        int bx = 32 + (id & 15);
        int by = id >> 4;
        gemm_core<1, 128, 64>(Xb, Wt, nullptr, Vt,
                              H, H, H, 0, 0, 0, bx, by, 0,
                              smem, smem + 8192);
    }
}

// Fused conversions.
__global__ __launch_bounds__(256)
void cvt_fused(const float* __restrict__ X, unsigned short* __restrict__ Xb,
               const float* __restrict__ W0, const float* __restrict__ W1,
               const float* __restrict__ W2, unsigned short* __restrict__ Wt) {
    __shared__ float t[64][65];
    if (blockIdx.x < 3072) {
        int id = blockIdx.x;
        int z = id >> 10, rem = id & 1023;
        const float* W = (z == 0) ? W0 : (z == 1) ? W1 : W2;
        unsigned short* Wo = Wt + (size_t)z * 4194304;
        int bx = (rem & 31) * 64, by = (rem >> 5) * 64;
        int tx = threadIdx.x & 63, ty = threadIdx.x >> 6;
#pragma unroll
        for (int r = 0; r < 64; r += 4)
            t[ty + r][tx] = W[(size_t)(by + ty + r) * 2048 + bx + tx];
        __syncthreads();
#pragma unroll
        for (int r = 0; r < 64; r += 4)
            Wo[(size_t)(bx + ty + r) * 2048 + by + tx] = f2bf(t[tx][ty + r]);
    } else {
        int id = blockIdx.x - 3072;
        const float4* X4 = (const float4*)X;
        short8* O8 = (short8*)Xb;
#pragma unroll
        for (int c = 0; c < 4; ++c) {
            size_t u = (size_t)c * (2048 * 256) + (size_t)id * 256 + threadIdx.x;
            float4 a = X4[u * 2];
            float4 b = X4[u * 2 + 1];
            short8 o;
            o[0] = f2bf(a.x); o[1] = f2bf(a.y); o[2] = f2bf(a.z); o[3] = f2bf(a.w);
            o[4] = f2bf(b.x); o[5] = f2bf(b.y); o[6] = f2bf(b.z); o[7] = f2bf(b.w);
            O8[u] = o;
        }
    }
}

extern "C" void kernel_launch(void* const* d_in, const int* in_sizes, int n_in,
                              void* d_out, int out_size, void* d_ws, size_t ws_size,
                              hipStream_t stream) {
    const int S = 2048, H = 2048;
    const long long MH = 16777216;
    const long long HH = 4194304;
    const long long SH = (long long)S * H;
    const long long SB = (long long)S * ABAND;

    const float* X  = (const float*)d_in[0];
    const float* WQ = (const float*)d_in[1];
    const float* WK = (const float*)d_in[2];
    const float* WV = (const float*)d_in[3];
    float* out = (float*)d_out;

    unsigned short* Xb    = (unsigned short*)d_ws;
    unsigned short* WtAll = Xb + MH;
    unsigned short* Qb    = WtAll + 3 * HH;
    unsigned short* Kb    = Qb + MH;
    unsigned short* Vt    = Kb + MH;
    unsigned short* att   = Vt + MH;

    cvt_fused<<<5120, 256, 0, stream>>>(X, Xb, WQ, WK, WV, WtAll);

    // s1a: Q,K projection, 8-phase 256^2 (16x32 grid = 512 blocks)
    qk_8phase<<<dim3(16, 32), 512, 0, stream>>>(Xb, WtAll, Qb, Kb);

    // fused: att (360 blocks, first) + V-projection (1024 blocks)
    fused_vatt<<<1384, 256, 0, stream>>>(Xb, WtAll, Qb, Kb, att, Vt);

    // s4: out = att_b x V, banded k-loop, XCD-chunked (1024 = 8*128)
    gemm_bt<4, 128, 64><<<1024, 256, 0, stream>>>(att, Vt, out, nullptr,
                                                  ABAND, 8192, S, SB, 2048, SH);
}

// Round 15
// 425.685 us; speedup vs baseline: 1.1128x; 1.1128x over previous
//
#include <hip/hip_runtime.h>
#include <math.h>

// SimpleRetention bf16 MFMA, round 18 = final revert to the session-best
// configuration (round 14/16 source; measured 411.0us r11, 422.0us r13 —
// run-to-run noise +/-11us on identical code).
// Round-17's derived-waits 8-phase qk kernel REGRESSED (203us @ 28% MfmaUtil
// vs 146us @ 46% for the 2-phase core) — third and final 8-phase attempt;
// structure-null confirmed per pre-registered read.
// Config: s1a Q,K projection (32x64, proven 128^2/BK64 core); fused
// att(360, XCD-chunked, banded)+V-proj(1024) overlap dispatch; s4 BN=128
// XCD-chunked 1024 with banded k-start; banded att storage (384 cols,
// band 2by-4, error bound 500x under threshold); fused cvt.

typedef __attribute__((ext_vector_type(8))) short short8;
typedef __attribute__((ext_vector_type(4))) float f32x4;
typedef __attribute__((ext_vector_type(4))) unsigned short us4;

#define BM 128
#define ABAND 384

static __device__ __forceinline__ unsigned short f2bf(float f) {
    unsigned int u = __float_as_uint(f);
    u += 0x7FFFu + ((u >> 16) & 1u);   // RNE
    return (unsigned short)(u >> 16);
}

static __device__ __forceinline__ void gload16(const unsigned short* g, unsigned short* l) {
    __builtin_amdgcn_global_load_lds(
        (const __attribute__((address_space(1))) unsigned int*)g,
        (__attribute__((address_space(3))) unsigned int*)l, 16, 0, 0);
}

// STAGE: 1 = QKV projection epilogues (mode by colBase: Q/K xpos, V transpose)
//        3 = att_b = (Q K^T)*decay (banded storage)
//        4 = out = att_b x V (banded k-loop)
template <int STAGE, int BNt, int BKt>
static __device__ __forceinline__ void gemm_core(
    const unsigned short* __restrict__ A,
    const unsigned short* __restrict__ Bt,
    void* __restrict__ Cv,
    unsigned short* __restrict__ Cq,
    unsigned short* __restrict__ Ck,
    unsigned short* __restrict__ Cvt,
    int lda, int ldb, int Kd,
    long long sA, long long sB, long long sC,
    int bx, int by, int zb,
    unsigned short* As, unsigned short* Bs)
{
    constexpr int S = 2048, H = 2048;
    constexpr int NJ = BNt / 32;        // j-fragments per wave
    constexpr int KS = BKt / 32;        // MFMA k-steps per tile
    constexpr int CR = BKt / 8;         // 16B chunks per row
    constexpr int RG = 64 / CR;         // rows per gload16
    constexpr int GA = 32 / RG;         // A gloads per thread
    constexpr int GB = (BNt / 4) / RG;  // B gloads per thread

    const int rowBase = by * BM;
    const int colBase = bx * BNt;

    A  += (long long)zb * sA;
    Bt += (long long)zb * sB;

    const int tid  = threadIdx.x;
    const int wave = tid >> 6;
    const int lane = tid & 63;
    const int wm = (wave & 1) * 64;
    const int wn = (wave >> 1) * (BNt / 2);

    f32x4 acc[4][NJ];
#pragma unroll
    for (int i = 0; i < 4; ++i)
#pragma unroll
        for (int j = 0; j < NJ; ++j) acc[i][j] = (f32x4){0.f, 0.f, 0.f, 0.f};

    int kmax = Kd;
    if (STAGE == 4) { int km = rowBase + BM; kmax = km < Kd ? km : Kd; } // causal
    int k0s = 0;
    if (STAGE == 4) {
        int kb0 = 2 * by - 4; k0s = (kb0 > 0 ? kb0 : 0) * 64;
        A -= k0s;   // banded storage: att_b[n][k - k0s] == dense att[n][k]
    }

    // Staging invariant: LDS chunk position p of row r holds source chunk
    // p ^ (r&7).  cpos = dest chunk, rig = row within gload group.
    const int cpos = lane % CR;
    const int rig  = lane / CR;
    const int waveArow = wave * 32;
    const int waveBrow = wave * (BNt / 4);
    unsigned short* lA = As + wave * (32 * BKt);
    unsigned short* lB = Bs + wave * ((BNt / 4) * BKt);

    auto stage_tile = [&](int kb) {
#pragma unroll
        for (int g = 0; g < GA; ++g) {
            int r = waveArow + g * RG + rig;
            gload16(A + (size_t)(rowBase + r) * lda + kb + ((cpos ^ (r & 7)) * 8),
                    lA + g * 512);
        }
#pragma unroll
        for (int g = 0; g < GB; ++g) {
            int r = waveBrow + g * RG + rig;
            gload16(Bt + (size_t)(colBase + r) * ldb + kb + ((cpos ^ (r & 7)) * 8),
                    lB + g * 512);
        }
    };

    stage_tile(k0s);

    const int fr = lane & 15;
    const int qd = lane >> 4;        // k-quad within 32-k step
    const int fsw = fr & 7;          // xor key per fragment row

    for (int k0 = k0s; k0 < kmax; k0 += BKt) {
        __syncthreads(); // tile k0 resident
        short8 aF[KS][4], bF[KS][NJ];
#pragma unroll
        for (int kk = 0; kk < KS; ++kk) {
#pragma unroll
            for (int i = 0; i < 4; ++i)
                aF[kk][i] = *(const short8*)&As[(wm + i * 16 + fr) * BKt + (((kk * 4 + qd) ^ fsw) * 8)];
#pragma unroll
            for (int j = 0; j < NJ; ++j)
                bF[kk][j] = *(const short8*)&Bs[(wn + j * 16 + fr) * BKt + (((kk * 4 + qd) ^ fsw) * 8)];
        }
        __syncthreads(); // all reads drained
        if (k0 + BKt < kmax) stage_tile(k0 + BKt);
#pragma unroll
        for (int kk = 0; kk < KS; ++kk)
#pragma unroll
            for (int i = 0; i < 4; ++i)
#pragma unroll
                for (int j = 0; j < NJ; ++j)
                    acc[i][j] = __builtin_amdgcn_mfma_f32_16x16x32_bf16(aF[kk][i], bF[kk][j], acc[i][j], 0, 0, 0);
    }

    // C/D layout: col = lane&15, row = (lane>>4)*4 + reg
    if (STAGE == 1) {
        const int mode = colBase >> 11; // 0=Q, 1=K, 2=V
        if (mode < 2) {
            unsigned short* Co = (mode == 0) ? Cq : Ck;
            const float psgn = (mode == 1) ? -1.953125e-3f : 1.953125e-3f; // ±1/512
#pragma unroll
            for (int j = 0; j < NJ; ++j) {
                int gc = (colBase & 2047) + wn + j * 16 + fr;
                float c0 = (float)(gc & ~1);
                float l2sv = log2f((c0 + 819.2f) * (1.0f / 2867.2f)) * psgn;
                float invf = exp2f(c0 * -0.0064881407f); // 10000^(-c0/2048)
                float s1, c1;
                sincosf(invf, &s1, &c1);
#pragma unroll
                for (int i = 0; i < 4; ++i) {
                    int gr0 = rowBase + wm + i * 16 + qd * 4;
                    float fn = (float)(gr0 & (S - 1));
                    float sN, cN;
                    sincosf(fn * invf, &sN, &cN);
#pragma unroll
                    for (int r = 0; r < 4; ++r) {
                        float scale = exp2f(fn * l2sv);
                        float cs = cN * scale, ss = sN * scale;
                        float v = acc[i][j][r];
                        float o = __shfl_xor(v, 1);
                        float res = (gc & 1) ? fmaf(v, cs, o * ss) : fmaf(v, cs, -o * ss);
                        Co[(size_t)(gr0 + r) * H + gc] = f2bf(res);
                        float sn2 = sN * c1 + cN * s1; // rotate by invf
                        cN = cN * c1 - sN * s1;
                        sN = sn2;
                        fn += 1.0f;
                    }
                }
            }
        } else { // V: store transposed Vt[h][8192]
#pragma unroll
            for (int j = 0; j < NJ; ++j) {
                int gh = (colBase & 2047) + wn + j * 16 + fr;
#pragma unroll
                for (int i = 0; i < 4; ++i) {
                    int gm0 = rowBase + wm + i * 16 + qd * 4;
                    us4 p;
#pragma unroll
                    for (int r = 0; r < 4; ++r) p[r] = f2bf(acc[i][j][r]);
                    *(us4*)&Cvt[(size_t)gh * 8192 + gm0] = p;
                }
            }
        }
    } else if (STAGE == 3) {
        unsigned short* att = (unsigned short*)Cv + (long long)zb * sC;
        const int kb0 = (2 * by - 4) > 0 ? (2 * by - 4) : 0;  // storage shift
        const int mshift = kb0 * 64;
#pragma unroll
        for (int j = 0; j < NJ; ++j) {
            int m = colBase + wn + j * 16 + fr;
#pragma unroll
            for (int i = 0; i < 4; ++i) {
                int n0 = rowBase + wm + i * 16 + qd * 4;
#pragma unroll
                for (int r = 0; r < 4; ++r) {
                    int d = n0 + r - m;
                    float v = (d >= 0) ? acc[i][j][r] * exp2f((float)d * -0.045803598f) : 0.0f;
                    att[(size_t)(n0 + r) * ABAND + (m - mshift)] = f2bf(v);
                }
            }
        }
    } else { // STAGE 4: C rows = n, cols = h -> out[n][h], 64B lane-runs
        float* Co = (float*)Cv + (long long)zb * sC;
#pragma unroll
        for (int j = 0; j < NJ; ++j) {
            int gh = colBase + wn + j * 16 + fr;
#pragma unroll
            for (int i = 0; i < 4; ++i) {
                int gn0 = rowBase + wm + i * 16 + qd * 4;
#pragma unroll
                for (int r = 0; r < 4; ++r)
                    Co[(size_t)(gn0 + r) * H + gh] = acc[i][j][r];
            }
        }
    }
}

// s1a (STAGE=1, Q/K cols only) and s4 (STAGE=4, XCD-chunked) wrappers
template <int STAGE, int BNt, int BKt>
__global__ __launch_bounds__(256)
void gemm_bt(const unsigned short* __restrict__ A,
             const unsigned short* __restrict__ Bt,
             void* __restrict__ Cv,
             unsigned short* __restrict__ Cq,
             unsigned short* __restrict__ Ck,
             unsigned short* __restrict__ Cvt,
             int lda, int ldb, int Kd,
             long long sA, long long sB, long long sC)
{
    __shared__ unsigned short As[BM * BKt];
    __shared__ unsigned short Bs[BNt * BKt];
    int bx, by, zb;
    if (STAGE == 4) {
        // XCD-chunked (1024 = 8*128): each chunk = 2 full Vt h-slabs;
        // within chunk: bx-major, then batch, then by descending (LPT).
        int id = blockIdx.x;
        int swz = (id & 7) * 128 + (id >> 3);
        bx = swz >> 6;
        int r = swz & 63;
        zb = r >> 4;
        by = 15 - (r & 15);
    } else {
        bx = blockIdx.x; by = blockIdx.y; zb = 0;
    }
    gemm_core<STAGE, BNt, BKt>(A, Bt, Cv, Cq, Ck, Cvt, lda, ldb, Kd,
                               sA, sB, sC, bx, by, zb, As, Bs);
}

// Fused: ids [0,360) = att blocks (latency-bound, spread first);
//        ids [360,1384) = V-projection blocks (backfill, hide att latency).
__global__ __launch_bounds__(256)
void fused_vatt(const unsigned short* __restrict__ Xb,
                const unsigned short* __restrict__ Wt,
                const unsigned short* __restrict__ Qb,
                const unsigned short* __restrict__ Kb,
                unsigned short* __restrict__ att,
                unsigned short* __restrict__ Vt)
{
    constexpr int S = 2048, H = 2048;
    constexpr long long SH = (long long)S * H;
    constexpr long long SB = (long long)S * ABAND;
    __shared__ unsigned short smem[16384];   // As 8192 + Bs up to 8192
    if (blockIdx.x < 360) {
        // att: XCD-chunked (360 = 8*45) + banded lower-tri decode (2by-4)
        int t = blockIdx.x;
        int swz = (t & 7) * 45 + (t >> 3);
        int zb = swz / 90;
        int tt = swz - zb * 90;
        int bx, by;
        if (tt < 6) {
            by = (tt < 2) ? 0 : 1;
            bx = tt - ((by == 0) ? 0 : 2);
        } else {
            by = 2 + (tt - 6) / 6;
            int kb0 = 2 * by - 4;
            bx = (kb0 > 0 ? kb0 : 0) + (tt - 6) % 6;
        }
        gemm_core<3, 64, 64>(Qb, Kb, att, nullptr, nullptr, nullptr,
                             H, H, H, SH, SH, SB, bx, by, zb,
                             smem, smem + 8192);
    } else {
        int id = blockIdx.x - 360;           // 0..1023
        int bx = 32 + (id & 15);             // V columns: colBase >= 4096
        int by = id >> 4;
        gemm_core<1, 128, 64>(Xb, Wt, nullptr, nullptr, nullptr, Vt,
                              H, H, H, 0, 0, 0, bx, by, 0,
                              smem, smem + 8192);
    }
}

// Fused conversions: blocks [0,3072) transpose W0..W2 -> WtAll bf16;
// blocks [3072, 5120) convert X fp32 -> bf16 (32 elems/thread).
__global__ __launch_bounds__(256)
void cvt_fused(const float* __restrict__ X, unsigned short* __restrict__ Xb,
               const float* __restrict__ W0, const float* __restrict__ W1,
               const float* __restrict__ W2, unsigned short* __restrict__ Wt) {
    __shared__ float t[64][65];
    if (blockIdx.x < 3072) {
        int id = blockIdx.x;
        int z = id >> 10, rem = id & 1023;
        const float* W = (z == 0) ? W0 : (z == 1) ? W1 : W2;
        unsigned short* Wo = Wt + (size_t)z * 4194304;
        int bx = (rem & 31) * 64, by = (rem >> 5) * 64;
        int tx = threadIdx.x & 63, ty = threadIdx.x >> 6;
#pragma unroll
        for (int r = 0; r < 64; r += 4)
            t[ty + r][tx] = W[(size_t)(by + ty + r) * 2048 + bx + tx];
        __syncthreads();
#pragma unroll
        for (int r = 0; r < 64; r += 4)
            Wo[(size_t)(bx + ty + r) * 2048 + by + tx] = f2bf(t[tx][ty + r]);
    } else {
        int id = blockIdx.x - 3072;          // 0..2047
        const float4* X4 = (const float4*)X;
        short8* O8 = (short8*)Xb;
#pragma unroll
        for (int c = 0; c < 4; ++c) {
            size_t u = (size_t)c * (2048 * 256) + (size_t)id * 256 + threadIdx.x;
            float4 a = X4[u * 2];
            float4 b = X4[u * 2 + 1];
            short8 o;
            o[0] = f2bf(a.x); o[1] = f2bf(a.y); o[2] = f2bf(a.z); o[3] = f2bf(a.w);
            o[4] = f2bf(b.x); o[5] = f2bf(b.y); o[6] = f2bf(b.z); o[7] = f2bf(b.w);
            O8[u] = o;
        }
    }
}

extern "C" void kernel_launch(void* const* d_in, const int* in_sizes, int n_in,
                              void* d_out, int out_size, void* d_ws, size_t ws_size,
                              hipStream_t stream) {
    const int S = 2048, H = 2048;
    const long long MH = 16777216;         // 8192*2048 elements
    const long long HH = 4194304;          // 2048*2048
    const long long SH = (long long)S * H; // per-batch stride
    const long long SB = (long long)S * ABAND; // banded att per-batch stride

    const float* X  = (const float*)d_in[0];
    const float* WQ = (const float*)d_in[1];
    const float* WK = (const float*)d_in[2];
    const float* WV = (const float*)d_in[3];
    float* out = (float*)d_out;

    unsigned short* Xb    = (unsigned short*)d_ws;
    unsigned short* WtAll = Xb + MH;        // [6144][2048]
    unsigned short* Qb    = WtAll + 3 * HH;
    unsigned short* Kb    = Qb + MH;
    unsigned short* Vt    = Kb + MH;        // [2048][8192]
    unsigned short* att   = Vt + MH;        // [4][2048][384] banded

    cvt_fused<<<5120, 256, 0, stream>>>(X, Xb, WQ, WK, WV, WtAll);

    // s1a: Q,K projection only (N = 4096)
    gemm_bt<1, 128, 64><<<dim3(32, 64), 256, 0, stream>>>(Xb, WtAll, nullptr, Qb, Kb, Vt,
                                                          H, H, H, 0, 0, 0);
    // fused: att (360 blocks, first) + V-projection (1024 blocks, backfill)
    fused_vatt<<<1384, 256, 0, stream>>>(Xb, WtAll, Qb, Kb, att, Vt);

    // s4: out = att_b x V, banded k-loop, XCD-chunked (1024 = 8*128)
    gemm_bt<4, 128, 64><<<1024, 256, 0, stream>>>(att, Vt, out, nullptr, nullptr, nullptr,
                                                  ABAND, 8192, S, SB, 2048, SH);
}